// Round 1
// baseline (574.544 us; speedup 1.0000x reference)
//
#include <hip/hip_runtime.h>
#include <hip/hip_bf16.h>
#include <cstdint>
#include <cstddef>

#define NTOKS  2048
#define DMODEL 1024
#define DFFN   4096
#define NEXP   8

typedef __attribute__((ext_vector_type(8))) short short8;
typedef __attribute__((ext_vector_type(4))) float f32x4;
typedef __attribute__((ext_vector_type(4))) unsigned short u16x4;
typedef __attribute__((ext_vector_type(8))) unsigned short u16x8;

// ---------------- workspace layout ----------------
static constexpr size_t alignup(size_t x) { return (x + 255) & ~(size_t)255; }
static constexpr size_t OFF_XB   = 0;                                            // (NTOKS+1) x DMODEL bf16 (last row zeros)
static constexpr size_t OFF_CNT  = alignup(OFF_XB + (size_t)(NTOKS + 1) * DMODEL * 2);
static constexpr size_t OFF_OFFS = OFF_CNT + 256;
static constexpr size_t OFF_TOKE = OFF_OFFS + 256;                               // NTOKS*2 int
static constexpr size_t OFF_TOKT = OFF_TOKE + (size_t)NTOKS * 2 * 4;             // NTOKS*2 int
static constexpr size_t OFF_TOKS = OFF_TOKT + (size_t)NTOKS * 2 * 4;             // NTOKS*2 float
static constexpr size_t OFF_CAP  = alignup(OFF_TOKS + (size_t)NTOKS * 2 * 4);    // NEXP*NTOKS int
static constexpr size_t OFF_H    = alignup(OFF_CAP + (size_t)NEXP * NTOKS * 4);  // (4096+128) x DFFN bf16
static constexpr size_t OFF_Y    = alignup(OFF_H + (size_t)(NTOKS * 2 + 128) * DFFN * 2); // 4096 x DMODEL f32

__device__ inline unsigned short f2bf(float f) {
  __hip_bfloat16 h = __float2bfloat16(f);
  return __builtin_bit_cast(unsigned short, h);
}

__device__ inline void gload16(const void* g, void* l) {
  __builtin_amdgcn_global_load_lds((const __attribute__((address_space(1))) unsigned int*)g,
                                   (__attribute__((address_space(3))) unsigned int*)l, 16, 0, 0);
}

// ---------------- kernel 1: x f32 -> bf16 (+zero row), zero counts ----------------
__global__ __launch_bounds__(256) void k_convert(const float* __restrict__ x,
                                                 unsigned short* __restrict__ xb,
                                                 int* __restrict__ cnt) {
  if (blockIdx.x == 0 && threadIdx.x < NEXP) cnt[threadIdx.x] = 0;
  size_t base = ((size_t)blockIdx.x * 256 + threadIdx.x) * 8;
  const size_t total = (size_t)(NTOKS + 1) * DMODEL;
  if (base >= total) return;
  u16x8 o;
  if (base < (size_t)NTOKS * DMODEL) {
    f32x4 a = *(const f32x4*)(x + base);
    f32x4 b = *(const f32x4*)(x + base + 4);
#pragma unroll
    for (int j = 0; j < 4; ++j) { o[j] = f2bf(a[j]); o[4 + j] = f2bf(b[j]); }
  } else {
#pragma unroll
    for (int j = 0; j < 8; ++j) o[j] = 0;
  }
  *(u16x8*)(xb + base) = o;
}

// ---------------- kernel 2: gate (one wave per token) ----------------
__global__ __launch_bounds__(256) void k_gate(const float* __restrict__ x,
                                              const float* __restrict__ Wg,
                                              const float* __restrict__ bg,
                                              int* __restrict__ cnt,
                                              int* __restrict__ tok_e,
                                              int* __restrict__ tok_t,
                                              float* __restrict__ tok_s,
                                              int* __restrict__ cap) {
  const int w = threadIdx.x >> 6, lane = threadIdx.x & 63;
  const int n = blockIdx.x * 4 + w;
  float acc[8];
#pragma unroll
  for (int e = 0; e < 8; ++e) acc[e] = 0.f;
  const float* xr = x + (size_t)n * DMODEL;
#pragma unroll 4
  for (int it = 0; it < DMODEL / 64; ++it) {
    int d = it * 64 + lane;
    float xv = xr[d];
    f32x4 w0 = *(const f32x4*)(Wg + d * 8);
    f32x4 w1 = *(const f32x4*)(Wg + d * 8 + 4);
#pragma unroll
    for (int j = 0; j < 4; ++j) { acc[j] += xv * w0[j]; acc[4 + j] += xv * w1[j]; }
  }
#pragma unroll
  for (int e = 0; e < 8; ++e)
#pragma unroll
    for (int off = 32; off; off >>= 1) acc[e] += __shfl_xor(acc[e], off, 64);
  if (lane == 0) {
    float l[8];
#pragma unroll
    for (int e = 0; e < 8; ++e) l[e] = acc[e] + bg[e];
    int i0 = 0; float v0 = l[0];
#pragma unroll
    for (int e = 1; e < 8; ++e) if (l[e] > v0) { v0 = l[e]; i0 = e; }
    int i1 = (i0 == 0) ? 1 : 0; float v1 = l[i1];
#pragma unroll
    for (int e = 0; e < 8; ++e) if (e != i0 && l[e] > v1) { v1 = l[e]; i1 = e; }
    float t = expf(v1 - v0);
    float inv = 1.f / (1.f + t);
    float s0 = inv, s1 = t * inv;
    int t0 = atomicAdd(&cnt[i0], 1);
    int t1 = atomicAdd(&cnt[i1], 1);
    cap[i0 * NTOKS + t0] = n;
    cap[i1 * NTOKS + t1] = n;
    tok_e[2 * n] = i0; tok_e[2 * n + 1] = i1;
    tok_t[2 * n] = t0; tok_t[2 * n + 1] = t1;
    tok_s[2 * n] = s0; tok_s[2 * n + 1] = s1;
  }
}

// ---------------- kernel 3: offsets = exclusive scan of counts ----------------
__global__ void k_scan(const int* __restrict__ cnt, int* __restrict__ offs) {
  if (threadIdx.x == 0) {
    int s = 0;
#pragma unroll
    for (int e = 0; e < NEXP; ++e) { offs[e] = s; s += cnt[e]; }
  }
}

// ---------------- grouped GEMM (BM=128, BK=32, 4 waves, mfma 16x16x32 bf16) ----------------
// FIRST:  A = xb gathered by token list, B = W1[e] (f32, converted in staging),
//         epilogue: h = relu(acc + b1[e]) as bf16
// !FIRST: A = h (contiguous slots),     B = W2[e],
//         epilogue: y = acc (f32)
template <int KTOT, int NTOT, int BN, bool FIRST>
__global__ __launch_bounds__(256) void k_gemm(const unsigned short* __restrict__ Asrc,
                                              const float* __restrict__ Wsrc,
                                              const float* __restrict__ bias,
                                              const int* __restrict__ cnt,
                                              const int* __restrict__ offs,
                                              const int* __restrict__ cap,
                                              unsigned short* __restrict__ hout,
                                              float* __restrict__ yout) {
  const int e = blockIdx.y >> 4, tile = blockIdx.y & 15;
  const int c = cnt[e];
  const int t0 = tile * 128;
  if (t0 >= c) return;
  const int base = offs[e] + t0;
  const int n0 = blockIdx.x * BN;

  const int tid = threadIdx.x, w = tid >> 6, lane = tid & 63;
  const int l15 = lane & 15, lq = lane >> 4;
  constexpr int WGC = BN / 64;        // wave-grid cols: 2 (BN=128) or 1 (BN=64)
  constexpr int WGR = 4 / WGC;        // wave-grid rows
  constexpr int MR = 128 / (WGR * 16);
  constexpr int NR = BN / (WGC * 16);
  const int wr = w / WGC, wc = w % WGC;

  __shared__ unsigned short As[128 * 32];
  __shared__ unsigned short Bs[BN * 32];

  // --- A staging source pointers (2 rounds of 256x16B = 128x32 bf16) ---
  const int row0 = tid >> 2, row1 = 64 + (tid >> 2), ch = tid & 3;
  size_t arow0, arow1;
  if constexpr (FIRST) {
    int ta0 = (t0 + row0 < c) ? cap[e * NTOKS + t0 + row0] : NTOKS;
    int ta1 = (t0 + row1 < c) ? cap[e * NTOKS + t0 + row1] : NTOKS;
    arow0 = (size_t)ta0 * KTOT;
    arow1 = (size_t)ta1 * KTOT;
  } else {
    arow0 = (size_t)(base + row0) * KTOT;
    arow1 = (size_t)(base + row1) * KTOT;
  }
  const unsigned short* aptr0 = Asrc + arow0 + ch * 8;
  const unsigned short* aptr1 = Asrc + arow1 + ch * 8;
  const float* We = Wsrc + (size_t)e * KTOT * NTOT;

  f32x4 acc[MR][NR] = {};

  for (int k0 = 0; k0 < KTOT; k0 += 32) {
    __syncthreads();
    // A: async global->LDS, per-lane source, wave-uniform dest
    gload16(aptr0 + k0, As + (w << 9));
    gload16(aptr1 + k0, As + 2048 + (w << 9));
    // B: f32 load -> bf16 convert -> transposed LDS tile [col][k]
    if constexpr (BN == 128) {
      const int tc = tid & 31, tr = tid >> 5;   // 4k x 4n per thread
      const float* bp = We + (size_t)(k0 + tr * 4) * NTOT + n0 + tc * 4;
      f32x4 v0 = *(const f32x4*)(bp);
      f32x4 v1 = *(const f32x4*)(bp + NTOT);
      f32x4 v2 = *(const f32x4*)(bp + 2 * (size_t)NTOT);
      f32x4 v3 = *(const f32x4*)(bp + 3 * (size_t)NTOT);
#pragma unroll
      for (int j = 0; j < 4; ++j) {
        u16x4 p = { f2bf(v0[j]), f2bf(v1[j]), f2bf(v2[j]), f2bf(v3[j]) };
        *(u16x4*)&Bs[(tc * 4 + j) * 32 + tr * 4] = p;
      }
    } else {
      if (tid < 128) {
        const int tc = tid & 15, tr = tid >> 4; // 4k x 4n per thread, 128 threads
        const float* bp = We + (size_t)(k0 + tr * 4) * NTOT + n0 + tc * 4;
        f32x4 v0 = *(const f32x4*)(bp);
        f32x4 v1 = *(const f32x4*)(bp + NTOT);
        f32x4 v2 = *(const f32x4*)(bp + 2 * (size_t)NTOT);
        f32x4 v3 = *(const f32x4*)(bp + 3 * (size_t)NTOT);
#pragma unroll
        for (int j = 0; j < 4; ++j) {
          u16x4 p = { f2bf(v0[j]), f2bf(v1[j]), f2bf(v2[j]), f2bf(v3[j]) };
          *(u16x4*)&Bs[(tc * 4 + j) * 32 + tr * 4] = p;
        }
      }
    }
    __syncthreads();

    short8 a[MR], b[NR];
#pragma unroll
    for (int m = 0; m < MR; ++m)
      a[m] = *(const short8*)&As[(wr * MR * 16 + m * 16 + l15) * 32 + lq * 8];
#pragma unroll
    for (int nn = 0; nn < NR; ++nn)
      b[nn] = *(const short8*)&Bs[(wc * NR * 16 + nn * 16 + l15) * 32 + lq * 8];
#pragma unroll
    for (int m = 0; m < MR; ++m)
#pragma unroll
      for (int nn = 0; nn < NR; ++nn)
        acc[m][nn] = __builtin_amdgcn_mfma_f32_16x16x32_bf16(a[m], b[nn], acc[m][nn], 0, 0, 0);
  }

  // --- epilogue ---
  if constexpr (FIRST) {
    const float* be = bias + (size_t)e * NTOT;
#pragma unroll
    for (int m = 0; m < MR; ++m) {
#pragma unroll
      for (int q = 0; q < 4; ++q) {
        int row = wr * MR * 16 + m * 16 + lq * 4 + q;
        if (t0 + row < c) {
          unsigned short* hr = hout + (size_t)(base + row) * NTOT;
#pragma unroll
          for (int nn = 0; nn < NR; ++nn) {
            int col = n0 + wc * NR * 16 + nn * 16 + l15;
            float v = acc[m][nn][q] + be[col];
            v = v > 0.f ? v : 0.f;
            hr[col] = f2bf(v);
          }
        }
      }
    }
  } else {
#pragma unroll
    for (int m = 0; m < MR; ++m) {
#pragma unroll
      for (int q = 0; q < 4; ++q) {
        int row = wr * MR * 16 + m * 16 + lq * 4 + q;
        if (t0 + row < c) {
          float* yr = yout + (size_t)(base + row) * NTOT;
#pragma unroll
          for (int nn = 0; nn < NR; ++nn) {
            int col = n0 + wc * NR * 16 + nn * 16 + l15;
            yr[col] = acc[m][nn][q];
          }
        }
      }
    }
  }
}

// ---------------- kernel 6: combine (one block per token) ----------------
__global__ __launch_bounds__(256) void k_combine(const float* __restrict__ y,
                                                 const float* __restrict__ b2,
                                                 const int* __restrict__ tok_e,
                                                 const int* __restrict__ tok_t,
                                                 const float* __restrict__ tok_s,
                                                 const int* __restrict__ offs,
                                                 float* __restrict__ out) {
  const int n = blockIdx.x, t = threadIdx.x;
  const int e0 = tok_e[2 * n], e1 = tok_e[2 * n + 1];
  const int s0i = offs[e0] + tok_t[2 * n];
  const int s1i = offs[e1] + tok_t[2 * n + 1];
  const float sc0 = tok_s[2 * n], sc1 = tok_s[2 * n + 1];
  f32x4 v0 = *(const f32x4*)(y + (size_t)s0i * DMODEL + t * 4);
  f32x4 v1 = *(const f32x4*)(y + (size_t)s1i * DMODEL + t * 4);
  f32x4 c0 = *(const f32x4*)(b2 + (size_t)e0 * DMODEL + t * 4);
  f32x4 c1 = *(const f32x4*)(b2 + (size_t)e1 * DMODEL + t * 4);
  f32x4 r = sc0 * (v0 + c0) + sc1 * (v1 + c1);
  *(f32x4*)(out + (size_t)n * DMODEL + t * 4) = r;
}

extern "C" void kernel_launch(void* const* d_in, const int* in_sizes, int n_in,
                              void* d_out, int out_size, void* d_ws, size_t ws_size,
                              hipStream_t stream) {
  const float* x  = (const float*)d_in[0];
  const float* Wg = (const float*)d_in[1];
  const float* bg = (const float*)d_in[2];
  const float* W1 = (const float*)d_in[3];
  const float* b1 = (const float*)d_in[4];
  const float* W2 = (const float*)d_in[5];
  const float* b2 = (const float*)d_in[6];
  float* out = (float*)d_out;

  char* ws = (char*)d_ws;
  unsigned short* xb = (unsigned short*)(ws + OFF_XB);
  int*   cnt   = (int*)(ws + OFF_CNT);
  int*   offs  = (int*)(ws + OFF_OFFS);
  int*   tok_e = (int*)(ws + OFF_TOKE);
  int*   tok_t = (int*)(ws + OFF_TOKT);
  float* tok_s = (float*)(ws + OFF_TOKS);
  int*   cap   = (int*)(ws + OFF_CAP);
  unsigned short* h = (unsigned short*)(ws + OFF_H);
  float* y = (float*)(ws + OFF_Y);

  const int convBlocks = (int)(((size_t)(NTOKS + 1) * DMODEL / 8 + 255) / 256);
  k_convert<<<convBlocks, 256, 0, stream>>>(x, xb, cnt);
  k_gate<<<NTOKS / 4, 256, 0, stream>>>(x, Wg, bg, cnt, tok_e, tok_t, tok_s, cap);
  k_scan<<<1, 64, 0, stream>>>(cnt, offs);
  k_gemm<DMODEL, DFFN, 128, true><<<dim3(DFFN / 128, NEXP * 16), 256, 0, stream>>>(
      xb, W1, b1, cnt, offs, cap, h, nullptr);
  k_gemm<DFFN, DMODEL, 64, false><<<dim3(DMODEL / 64, NEXP * 16), 256, 0, stream>>>(
      h, W2, nullptr, cnt, offs, cap, nullptr, y);
  k_combine<<<NTOKS, 256, 0, stream>>>(y, b2, tok_e, tok_t, tok_s, offs, out);
}